// Round 1
// baseline (154.276 us; speedup 1.0000x reference)
//
#include <hip/hip_runtime.h>

// B=8, C=256, N=2048, fp32 in/out.
// attn_b = (Ap_b x_b + cvec_b 1^T) / S
//   Ap_b = T1_b W3 + wvsx_b (x) u2 + bv (x) v2_b      (f16 hi/lo split MFMA)
//   T1_b = Wv G_b,  W3 = Wq^T Wk,  G_b = x_b x_b^T (symmetric)
//   u2 = Wk^T bq, w1 = Wq^T bk, s1 = bq.bk, sx_b = rowsum(x_b)
//   v2_b = W3^T sx_b + N u2;  s2_b = sx.w1 + N s1;  S = sum_b [v2.sx + N s2]
//   cvec_b = T1.w1 + wvsx*s1 + bv*s2    (computed inside ap)
// 4 serial nodes. This round: fix grid starvation + exposed load latency in the
// middle kernels. k2-t1 and ap now use 32x64 tiles (256 blocks each -> full GPU,
// was 128/144 blocks = half idle at 1 wave/SIMD) and register double-buffered
// staging (issue next chunk's loads right after the post-write barrier so the
// FMA phase covers LLC latency -- k1's proven pattern). k4 gains the same
// prefetch for its A/x staging ahead of the MFMA phases. Arithmetic order is
// preserved exactly everywhere (same k and ksl ordering) -> identical absmax.

typedef _Float16 half8 __attribute__((ext_vector_type(8)));
typedef _Float16 half4 __attribute__((ext_vector_type(4)));
typedef _Float16 half2v __attribute__((ext_vector_type(2)));
typedef float f4v __attribute__((ext_vector_type(4)));

#define GP  40   // LDS pitch (halves), A panels / gemmG (16B-aligned rows)
#define GPB 36   // gemmF B panel pitch: 18-dword row stride -> 2-way (free) banking

// ---------------- K1: gemmG splitK=8 (+rowsum) | W3 | u2/w1/s1 ----------------
// blocks 0..191: gemmG; 192..207: W3 tiles; 208: u2/w1/s1 + zero S.
__launch_bounds__(256)
__global__ void k1_kernel(const float* __restrict__ x, const float* __restrict__ Wq,
                          const float* __restrict__ Wk, const float* __restrict__ bq,
                          const float* __restrict__ bk, float* __restrict__ sxpart,
                          float* __restrict__ W3, float* __restrict__ u2,
                          float* __restrict__ w1, float* __restrict__ s1,
                          float* __restrict__ S, float* __restrict__ Gpart) {
    __shared__ __align__(16) char smem[40960];
    const int blk = blockIdx.x, t = threadIdx.x;
    if (blk < 192) {
        _Float16* Ah = (_Float16*)smem;
        _Float16* Al = Ah + 128 * GP;
        _Float16* Bh = Al + 128 * GP;
        _Float16* Bl = Bh + 128 * GP;
        // XCD swizzle: tiles 0..2 of the same y are 64 apart -> identical blk%8
        // -> same XCD -> shared x rows hit that XCD's L2 instead of HBM twice.
        const int tileId = blk >> 6;           // 0..2
        const int y = blk & 63;                // 0..63
        const int b = y >> 3, ks = y & 7;
        const int r0 = (tileId == 2) ? 128 : 0;
        const int c0 = (tileId == 0) ? 0 : 128;
        const bool diag = (tileId != 1);
        const float* xb = x + (long)b * 524288;

        const int lane = t & 63, wave = t >> 6;
        const int wy = wave >> 1, wx = wave & 1;
        const int mIn = lane & 15, quad = lane >> 4;

        f4v acc[4][4] = {};
        const int aBase = (wy * 64 + mIn) * GP + quad * 8;
        const int bBase = (wx * 64 + mIn) * GP + quad * 8;
        const int srow = t >> 3;               // 0..31
        const int skq  = (t & 7) * 4;          // 0..28
        float rs[4] = {};                      // rowsum partials (diag only)

        float4 pa[4], pb[4];
        int kk = ks * 256;
        #pragma unroll
        for (int i = 0; i < 4; ++i) {
            pa[i] = *(const float4*)&xb[(long)(r0 + srow + i * 32) * 2048 + kk + skq];
            if (!diag) pb[i] = *(const float4*)&xb[(long)(c0 + srow + i * 32) * 2048 + kk + skq];
        }

        for (int kb = 0; kb < 8; ++kb) {
            if (kb) __syncthreads();
            #pragma unroll
            for (int i = 0; i < 4; ++i) {
                const int row = srow + i * 32;
                half4 hv, lv;
                hv[0] = (_Float16)pa[i].x; lv[0] = (_Float16)(pa[i].x - (float)hv[0]);
                hv[1] = (_Float16)pa[i].y; lv[1] = (_Float16)(pa[i].y - (float)hv[1]);
                hv[2] = (_Float16)pa[i].z; lv[2] = (_Float16)(pa[i].z - (float)hv[2]);
                hv[3] = (_Float16)pa[i].w; lv[3] = (_Float16)(pa[i].w - (float)hv[3]);
                *(half4*)&Ah[row * GP + skq] = hv;
                *(half4*)&Al[row * GP + skq] = lv;
                if (diag) {
                    rs[i] += pa[i].x + pa[i].y + pa[i].z + pa[i].w;
                } else {
                    half4 hb, lb;
                    hb[0] = (_Float16)pb[i].x; lb[0] = (_Float16)(pb[i].x - (float)hb[0]);
                    hb[1] = (_Float16)pb[i].y; lb[1] = (_Float16)(pb[i].y - (float)hb[1]);
                    hb[2] = (_Float16)pb[i].z; lb[2] = (_Float16)(pb[i].z - (float)hb[2]);
                    hb[3] = (_Float16)pb[i].w; lb[3] = (_Float16)(pb[i].w - (float)hb[3]);
                    *(half4*)&Bh[row * GP + skq] = hb;
                    *(half4*)&Bl[row * GP + skq] = lb;
                }
            }
            __syncthreads();
            kk += 32;
            if (kb < 7) {
                #pragma unroll
                for (int i = 0; i < 4; ++i) {
                    pa[i] = *(const float4*)&xb[(long)(r0 + srow + i * 32) * 2048 + kk + skq];
                    if (!diag) pb[i] = *(const float4*)&xb[(long)(c0 + srow + i * 32) * 2048 + kk + skq];
                }
            }
            const _Float16* BhP = diag ? Ah : Bh;
            const _Float16* BlP = diag ? Al : Bl;
            #pragma unroll
            for (int ph = 0; ph < 3; ++ph) {
                const _Float16* As = (ph == 2) ? Al : Ah;
                const _Float16* Bs = (ph == 1) ? BlP : BhP;
                half8 af[4], bf[4];
                #pragma unroll
                for (int i = 0; i < 4; ++i) {
                    af[i] = *(const half8*)&As[aBase + i * 16 * GP];
                    bf[i] = *(const half8*)&Bs[bBase + i * 16 * GP];
                }
                #pragma unroll
                for (int i = 0; i < 4; ++i)
                    #pragma unroll
                    for (int j = 0; j < 4; ++j)
                        acc[i][j] = __builtin_amdgcn_mfma_f32_16x16x32_f16(af[i], bf[j], acc[i][j], 0, 0, 0);
            }
        }

        if (diag) {
            #pragma unroll
            for (int i = 0; i < 4; ++i) {
                rs[i] += __shfl_xor(rs[i], 1);
                rs[i] += __shfl_xor(rs[i], 2);
                rs[i] += __shfl_xor(rs[i], 4);
            }
            if ((t & 7) == 0) {
                #pragma unroll
                for (int i = 0; i < 4; ++i)
                    sxpart[ks * 2048 + b * 256 + r0 + srow + i * 32] = rs[i];
            }
        }

        float* D = Gpart + ((long)(ks * 8 + b) << 16);
        #pragma unroll
        for (int i = 0; i < 4; ++i)
            #pragma unroll
            for (int j = 0; j < 4; ++j) {
                const int row = r0 + wy * 64 + i * 16 + quad * 4;
                const int col = c0 + wx * 64 + j * 16 + mIn;
                #pragma unroll
                for (int r = 0; r < 4; ++r)
                    D[(row + r) * 256 + col] = acc[i][j][r];
                if (tileId == 1)
                    *(float4*)&D[(long)col * 256 + row] =
                        make_float4(acc[i][j][0], acc[i][j][1], acc[i][j][2], acc[i][j][3]);
            }
    } else if (blk < 208) {
        float* ldsA = (float*)smem;
        float* ldsB = ldsA + 16 * 68;
        const int tile = blk - 192;
        const int r0 = (tile >> 2) * 64, j0 = (tile & 3) * 64;
        const int tx = t & 15, ty = t >> 4;
        float acc[4][4] = {};
        for (int kk = 0; kk < 256; kk += 16) {
            *(float4*)&ldsA[ty * 68 + tx * 4] = *(const float4*)&Wq[(long)(kk + ty) * 256 + r0 + tx * 4];
            *(float4*)&ldsB[ty * 68 + tx * 4] = *(const float4*)&Wk[(long)(kk + ty) * 256 + j0 + tx * 4];
            __syncthreads();
            #pragma unroll
            for (int k = 0; k < 16; ++k) {
                const float4 av4 = *(const float4*)&ldsA[k * 68 + ty * 4];
                const float4 bv4 = *(const float4*)&ldsB[k * 68 + tx * 4];
                const float ar[4] = {av4.x, av4.y, av4.z, av4.w};
                const float br[4] = {bv4.x, bv4.y, bv4.z, bv4.w};
                #pragma unroll
                for (int i = 0; i < 4; ++i)
                    #pragma unroll
                    for (int j = 0; j < 4; ++j)
                        acc[i][j] = fmaf(ar[i], br[j], acc[i][j]);
            }
            __syncthreads();
        }
        #pragma unroll
        for (int i = 0; i < 4; ++i)
            *(float4*)&W3[(long)(r0 + ty * 4 + i) * 256 + j0 + tx * 4] =
                make_float4(acc[i][0], acc[i][1], acc[i][2], acc[i][3]);
    } else {
        float* sbq = (float*)smem;
        float* sbk = sbq + 256;
        float* red = sbk + 256;
        if (t == 0) S[0] = 0.0f;
        sbq[t] = bq[t]; sbk[t] = bk[t];
        __syncthreads();
        float u = 0.0f, w = 0.0f;
        #pragma unroll 8
        for (int c = 0; c < 256; ++c) {
            u = fmaf(Wk[(long)c * 256 + t], sbq[c], u);   // coalesced columns
            w = fmaf(Wq[(long)c * 256 + t], sbk[c], w);
        }
        u2[t] = u; w1[t] = w;
        red[t] = sbq[t] * sbk[t]; __syncthreads();
        for (int h = 128; h > 0; h >>= 1) { if (t < h) red[t] += red[t + h]; __syncthreads(); }
        if (t == 0) s1[0] = red[0];
    }
}

// ---------------- K2: t1 (0..255, 32x64 tiles) | prep2 (256..263) | wvsx (264..271) ----------------
__launch_bounds__(256)
__global__ void k2_kernel(const float* __restrict__ Wv, const float* __restrict__ Gpart,
                          const float* __restrict__ W3, const float* __restrict__ u2,
                          const float* __restrict__ w1, const float* __restrict__ s1p,
                          const float* __restrict__ sxpart, float* __restrict__ T1,
                          float* __restrict__ v2, float* __restrict__ s2,
                          float* __restrict__ wvsx, float* __restrict__ S) {
    __shared__ __align__(16) char smem[40960];
    const int blk = blockIdx.x, t = threadIdx.x;
    if (blk < 256) {
        // T1_b = Wv * G_b, 32x64 tiles -> 256 blocks (full GPU; was 128).
        // XCD swizzle: the 8 r0-blocks sharing one (b,j0) Gpart B-panel are 32
        // apart -> identical blk%8 -> same XCD -> panel read hits L2 7 of 8 times.
        float* ldsA = (float*)smem;            // [32 k][34] transposed Wv panel
        float* ldsB = ldsA + 32 * 34;          // [32 k][68] reduced G panel
        const int r0 = (blk >> 5) * 32;        // 0..224
        const int g  = blk & 31;
        const int b  = g >> 2;
        const int j0 = (g & 3) * 64;
        const int tx = t & 15, ty = t >> 4;
        const int ar = t >> 3, ak4 = (t & 7) * 4;
        const float* Gb = Gpart + (long)b * 65536 + j0;
        float acc[2][4] = {};

        // register double-buffer: 1 Wv float4 + 16 Gpart float4 in flight
        f4v pa, pg[2][8];
        pa = *(const f4v*)&Wv[(long)(r0 + ar) * 256 + ak4];
        #pragma unroll
        for (int s = 0; s < 2; ++s)
            #pragma unroll
            for (int ksl = 0; ksl < 8; ++ksl)
                pg[s][ksl] = *(const f4v*)&Gb[(long)ksl * 524288 + (long)(s * 16 + ty) * 256 + tx * 4];

        for (int c = 0; c < 8; ++c) {
            const int kk = c * 32;
            // consume prefetched regs -> LDS
            ldsA[(ak4 + 0) * 34 + ar] = pa[0];
            ldsA[(ak4 + 1) * 34 + ar] = pa[1];
            ldsA[(ak4 + 2) * 34 + ar] = pa[2];
            ldsA[(ak4 + 3) * 34 + ar] = pa[3];
            #pragma unroll
            for (int s = 0; s < 2; ++s) {
                f4v bs = pg[s][0];
                #pragma unroll
                for (int ksl = 1; ksl < 8; ++ksl) bs += pg[s][ksl];
                *(f4v*)&ldsB[(s * 16 + ty) * 68 + tx * 4] = bs;
            }
            __syncthreads();
            if (c < 7) {                       // issue next chunk's loads; FMA hides latency
                const int kn = kk + 32;
                pa = *(const f4v*)&Wv[(long)(r0 + ar) * 256 + kn + ak4];
                #pragma unroll
                for (int s = 0; s < 2; ++s)
                    #pragma unroll
                    for (int ksl = 0; ksl < 8; ++ksl)
                        pg[s][ksl] = *(const f4v*)&Gb[(long)ksl * 524288 + (long)(kn + s * 16 + ty) * 256 + tx * 4];
            }
            #pragma unroll
            for (int k = 0; k < 32; ++k) {
                const float2 av2 = *(const float2*)&ldsA[k * 34 + ty * 2];
                const float4 bv4 = *(const float4*)&ldsB[k * 68 + tx * 4];
                acc[0][0] = fmaf(av2.x, bv4.x, acc[0][0]);
                acc[0][1] = fmaf(av2.x, bv4.y, acc[0][1]);
                acc[0][2] = fmaf(av2.x, bv4.z, acc[0][2]);
                acc[0][3] = fmaf(av2.x, bv4.w, acc[0][3]);
                acc[1][0] = fmaf(av2.y, bv4.x, acc[1][0]);
                acc[1][1] = fmaf(av2.y, bv4.y, acc[1][1]);
                acc[1][2] = fmaf(av2.y, bv4.z, acc[1][2]);
                acc[1][3] = fmaf(av2.y, bv4.w, acc[1][3]);
            }
            __syncthreads();
        }
        float* D = T1 + (long)b * 65536;
        #pragma unroll
        for (int i = 0; i < 2; ++i)
            *(float4*)&D[(long)(r0 + ty * 2 + i) * 256 + j0 + tx * 4] =
                make_float4(acc[i][0], acc[i][1], acc[i][2], acc[i][3]);
    } else if (blk < 264) {
        float* ssx = (float*)smem;
        float* red = ssx + 256;
        const int b = blk - 256, j = t;
        float sxv = 0.0f;
        #pragma unroll
        for (int ks = 0; ks < 8; ++ks) sxv += sxpart[ks * 2048 + b * 256 + j];
        ssx[j] = sxv;
        __syncthreads();
        float vr = 0.0f;
        #pragma unroll 8
        for (int c = 0; c < 256; ++c) vr = fmaf(W3[(long)c * 256 + j], ssx[c], vr); // coalesced
        const float v2j = vr + 2048.0f * u2[j];
        v2[b * 256 + j] = v2j;
        red[j] = v2j * sxv; __syncthreads();
        for (int h = 128; h > 0; h >>= 1) { if (j < h) red[j] += red[j + h]; __syncthreads(); }
        const float sd1 = red[0];
        __syncthreads();
        red[j] = sxv * w1[j]; __syncthreads();
        for (int h = 128; h > 0; h >>= 1) { if (j < h) red[j] += red[j + h]; __syncthreads(); }
        if (j == 0) {
            const float s2v = red[0] + 2048.0f * s1p[0];
            s2[b] = s2v;
            atomicAdd(S, sd1 + 2048.0f * s2v);
        }
    } else {
        float* wtile = (float*)smem;           // 32 x 256
        float* sxs = wtile + 8192;             // 2048
        const int r0w = (blk - 264) * 32;
        #pragma unroll
        for (int p = 0; p < 8; ++p) {
            const int f = t + p * 256;
            const int row = f >> 6, c4 = f & 63;
            *(float4*)&wtile[row * 256 + c4 * 4] = *(const float4*)&Wv[(long)(r0w + row) * 256 + c4 * 4];
        }
        #pragma unroll
        for (int p = 0; p < 8; ++p) {
            const int f = t + p * 256;
            float s = 0.0f;
            #pragma unroll
            for (int ks = 0; ks < 8; ++ks) s += sxpart[ks * 2048 + f];
            sxs[f] = s;
        }
        __syncthreads();
        const int r = t >> 3, q = t & 7;       // 32 rows x 8 k-groups
        float acc[8] = {};
        for (int ci = 0; ci < 32; ++ci) {
            const float wv = wtile[r * 256 + q * 32 + ci];
            #pragma unroll
            for (int b = 0; b < 8; ++b) acc[b] = fmaf(wv, sxs[b * 256 + q * 32 + ci], acc[b]);
        }
        #pragma unroll
        for (int b = 0; b < 8; ++b) {
            acc[b] += __shfl_xor(acc[b], 1);
            acc[b] += __shfl_xor(acc[b], 2);
            acc[b] += __shfl_xor(acc[b], 4);
        }
        if (q == 0) {
            #pragma unroll
            for (int b = 0; b < 8; ++b) wvsx[b * 256 + r0w + r] = acc[b];
        }
    }
}

// ---------------- K3: Ap = T1 W3 + wvsx(x)u2 + bv(x)v2 -> f16 hi/lo; cvec fold ----------------
// 32x64 tiles, grid (4,8,8) = 256 blocks (was 128 = half GPU idle) + reg prefetch.
__launch_bounds__(256)
__global__ void ap_kernel(const float* __restrict__ T1, const float* __restrict__ W3,
                          const float* __restrict__ wvsx, const float* __restrict__ u2,
                          const float* __restrict__ bv, const float* __restrict__ v2,
                          const float* __restrict__ w1, const float* __restrict__ s1p,
                          const float* __restrict__ s2, _Float16* __restrict__ Aph,
                          _Float16* __restrict__ Apl, float* __restrict__ cvec) {
    __shared__ __align__(16) float ldsA[32 * 34];   // [32 k][34] transposed T1 panel
    __shared__ __align__(16) float ldsB[32 * 68];   // [32 k][68] W3 panel
    __shared__ float sw1[256];
    const int b = blockIdx.z;
    const int r0 = blockIdx.y * 32, j0 = blockIdx.x * 64;
    const float* A = T1 + (long)b * 65536;
    const int t = threadIdx.x, tx = t & 15, ty = t >> 4;
    const int ar = t >> 3, ak4 = (t & 7) * 4;
    sw1[t] = w1[t];
    float acc[2][4] = {};
    float dot[2] = {};

    f4v pa, pb[2];
    pa = *(const f4v*)&A[(long)(r0 + ar) * 256 + ak4];
    pb[0] = *(const f4v*)&W3[(long)(ty) * 256 + j0 + tx * 4];
    pb[1] = *(const f4v*)&W3[(long)(16 + ty) * 256 + j0 + tx * 4];

    for (int c = 0; c < 8; ++c) {
        const int kk = c * 32;
        ldsA[(ak4 + 0) * 34 + ar] = pa[0];
        ldsA[(ak4 + 1) * 34 + ar] = pa[1];
        ldsA[(ak4 + 2) * 34 + ar] = pa[2];
        ldsA[(ak4 + 3) * 34 + ar] = pa[3];
        *(f4v*)&ldsB[ty * 68 + tx * 4] = pb[0];
        *(f4v*)&ldsB[(16 + ty) * 68 + tx * 4] = pb[1];
        __syncthreads();
        if (c < 7) {                            // prefetch next chunk under FMA
            const int kn = kk + 32;
            pa = *(const f4v*)&A[(long)(r0 + ar) * 256 + kn + ak4];
            pb[0] = *(const f4v*)&W3[(long)(kn + ty) * 256 + j0 + tx * 4];
            pb[1] = *(const f4v*)&W3[(long)(kn + 16 + ty) * 256 + j0 + tx * 4];
        }
        #pragma unroll
        for (int k = 0; k < 32; ++k) {
            const float2 av2 = *(const float2*)&ldsA[k * 34 + ty * 2];
            const float4 bv4 = *(const float4*)&ldsB[k * 68 + tx * 4];
            const float wk = sw1[kk + k];
            dot[0] = fmaf(av2.x, wk, dot[0]);
            dot[1] = fmaf(av2.y, wk, dot[1]);
            acc[0][0] = fmaf(av2.x, bv4.x, acc[0][0]);
            acc[0][1] = fmaf(av2.x, bv4.y, acc[0][1]);
            acc[0][2] = fmaf(av2.x, bv4.z, acc[0][2]);
            acc[0][3] = fmaf(av2.x, bv4.w, acc[0][3]);
            acc[1][0] = fmaf(av2.y, bv4.x, acc[1][0]);
            acc[1][1] = fmaf(av2.y, bv4.y, acc[1][1]);
            acc[1][2] = fmaf(av2.y, bv4.z, acc[1][2]);
            acc[1][3] = fmaf(av2.y, bv4.w, acc[1][3]);
        }
        __syncthreads();
    }
    #pragma unroll
    for (int i = 0; i < 2; ++i) {
        const int r = r0 + ty * 2 + i;
        const float e1 = wvsx[b * 256 + r], e3 = bv[r];
        half4 hv, lv;
        #pragma unroll
        for (int j = 0; j < 4; ++j) {
            const int col = j0 + tx * 4 + j;
            const float val = acc[i][j] + e1 * u2[col] + e3 * v2[b * 256 + col];
            hv[j] = (_Float16)val;
            lv[j] = (_Float16)(val - (float)hv[j]);
        }
        const long o = (long)b * 65536 + (long)r * 256 + j0 + tx * 4;
        *(half4*)&Aph[o] = hv;
        *(half4*)&Apl[o] = lv;
        if (j0 == 0 && tx == 0)
            cvec[b * 256 + r] = dot[i] + e1 * s1p[0] + e3 * s2[b];
    }
}

// ---------------- K4: out = (Ap x + cvec 1^T) / S ; x converted in-kernel ----------------
__launch_bounds__(256)
__global__ void gemmF_mfma(const _Float16* __restrict__ Aph, const _Float16* __restrict__ Apl,
                           const float* __restrict__ x, const float* __restrict__ Sptr,
                           const float* __restrict__ cvec, float* __restrict__ out) {
    __shared__ __align__(16) _Float16 Ah[128 * GP];
    __shared__ __align__(16) _Float16 Al[128 * GP];
    __shared__ __align__(16) _Float16 Bh[128 * GPB];
    __shared__ __align__(16) _Float16 Bl[128 * GPB];
    __shared__ __align__(16) float xt[32 * 132];

    const int n0 = blockIdx.x * 128;
    const int c0 = blockIdx.y * 128;
    const int b = blockIdx.z;
    const _Float16* Asrc_h = Aph + (long)b * 65536;
    const _Float16* Asrc_l = Apl + (long)b * 65536;
    const float* xb = x + (long)b * 524288;

    const int t = threadIdx.x;
    const int lane = t & 63, wave = t >> 6;
    const int wy = wave >> 1, wx = wave & 1;
    const int mIn = lane & 15, quad = lane >> 4;

    f4v acc[4][4] = {};
    const int aBase = (wy * 64 + mIn) * GP + quad * 8;
    const int bBase = (wx * 64 + mIn) * GPB + quad * 8;
    const int cn = t & 127;          // converter: n index
    const int ckh = (t >> 7) * 16;   // converter: k half-range

    // staging index precompute (static after unroll)
    int arow[2], ako[2], xk[4], xn[4];
    #pragma unroll
    for (int i = 0; i < 2; ++i) { const int idx = t + (i << 8); arow[i] = idx >> 2; ako[i] = (idx & 3) << 3; }
    #pragma unroll
    for (int p = 0; p < 4; ++p) { const int f = t + p * 256; xk[p] = f >> 5; xn[p] = f & 31; }

    // register prefetch of first tile
    uint4 pah[2], pal[2]; f4v px[4];
    #pragma unroll
    for (int i = 0; i < 2; ++i) {
        pah[i] = *(const uint4*)&Asrc_h[(long)(c0 + arow[i]) * 256 + ako[i]];
        pal[i] = *(const uint4*)&Asrc_l[(long)(c0 + arow[i]) * 256 + ako[i]];
    }
    #pragma unroll
    for (int p = 0; p < 4; ++p)
        px[p] = *(const f4v*)&xb[(long)xk[p] * 2048 + n0 + xn[p] * 4];

    for (int kk = 0; kk < 256; kk += 32) {
        #pragma unroll
        for (int i = 0; i < 2; ++i) {
            *(uint4*)&Ah[arow[i] * GP + ako[i]] = pah[i];
            *(uint4*)&Al[arow[i] * GP + ako[i]] = pal[i];
        }
        #pragma unroll
        for (int p = 0; p < 4; ++p)
            *(f4v*)&xt[xk[p] * 132 + xn[p] * 4] = px[p];
        __syncthreads();
        {
            _Float16 hs[16], ls[16];
            #pragma unroll
            for (int k = 0; k < 16; ++k) {
                const float v = xt[(ckh + k) * 132 + cn];      // 2-way LDS read (free)
                hs[k] = (_Float16)v;
                ls[k] = (_Float16)(v - (float)hs[k]);
            }
            #pragma unroll
            for (int k2 = 0; k2 < 8; ++k2) {
                half2v h2; h2[0] = hs[2 * k2]; h2[1] = hs[2 * k2 + 1];
                half2v l2; l2[0] = ls[2 * k2]; l2[1] = ls[2 * k2 + 1];
                *(half2v*)&Bh[cn * GPB + ckh + 2 * k2] = h2;   // 18-dword stride: 2-way (free)
                *(half2v*)&Bl[cn * GPB + ckh + 2 * k2] = l2;
            }
        }
        __syncthreads();
        if (kk < 224) {                         // prefetch next tile under MFMA phases
            const int kn = kk + 32;
            #pragma unroll
            for (int i = 0; i < 2; ++i) {
                pah[i] = *(const uint4*)&Asrc_h[(long)(c0 + arow[i]) * 256 + kn + ako[i]];
                pal[i] = *(const uint4*)&Asrc_l[(long)(c0 + arow[i]) * 256 + kn + ako[i]];
            }
            #pragma unroll
            for (int p = 0; p < 4; ++p)
                px[p] = *(const f4v*)&xb[(long)(kn + xk[p]) * 2048 + n0 + xn[p] * 4];
        }
        #pragma unroll
        for (int ph = 0; ph < 3; ++ph) {
            const _Float16* As = (ph == 2) ? Al : Ah;
            const _Float16* Bs = (ph == 1) ? Bl : Bh;
            half8 af[4], bf[4];
            #pragma unroll
            for (int i = 0; i < 4; ++i) {
                af[i] = *(const half8*)&As[aBase + i * 16 * GP];
                const half4 b0 = *(const half4*)&Bs[bBase + i * 16 * GPB];
                const half4 b1 = *(const half4*)&Bs[bBase + i * 16 * GPB + 4];
                bf[i] = __builtin_shufflevector(b0, b1, 0, 1, 2, 3, 4, 5, 6, 7);
            }
            #pragma unroll
            for (int i = 0; i < 4; ++i)
                #pragma unroll
                for (int j = 0; j < 4; ++j)
                    acc[i][j] = __builtin_amdgcn_mfma_f32_16x16x32_f16(af[i], bf[j], acc[i][j], 0, 0, 0);
        }
        __syncthreads();
    }

    const float invS = 1.0f / Sptr[0];
    float* ob = out + (long)b * 524288;
    const float* cv = cvec + b * 256;
    #pragma unroll
    for (int i = 0; i < 4; ++i)
        #pragma unroll
        for (int r = 0; r < 4; ++r) {
            const int row = c0 + wy * 64 + i * 16 + quad * 4 + r;
            const float c = cv[row];
            #pragma unroll
            for (int j = 0; j < 4; ++j) {
                const int col = n0 + wx * 64 + j * 16 + mIn;
                ob[(long)row * 2048 + col] = (acc[i][j][r] + c) * invS;
            }
        }
}

extern "C" void kernel_launch(void* const* d_in, const int* in_sizes, int n_in,
                              void* d_out, int out_size, void* d_ws, size_t ws_size,
                              hipStream_t stream) {
    const float* x  = (const float*)d_in[0];
    const float* Wq = (const float*)d_in[1];
    const float* bq = (const float*)d_in[2];
    const float* Wk = (const float*)d_in[3];
    const float* bk = (const float*)d_in[4];
    const float* Wv = (const float*)d_in[5];
    const float* bv = (const float*)d_in[6];
    float* out = (float*)d_out;
    float* ws  = (float*)d_ws;

    float* T1     = ws;                  // 524288
    float* W3     = ws + 524288;         // 65536
    float* sxpart = ws + 589824;         // 8*2048
    float* wvsx   = ws + 606208;         // 2048
    float* v2     = ws + 608256;         // 2048
    float* cvec   = ws + 610304;         // 2048
    float* s2     = ws + 612352;         // 8
    float* u2     = ws + 612360;         // 256
    float* w1     = ws + 612616;         // 256
    float* s1     = ws + 612872;         // 1
    float* S      = ws + 612873;         // 1
    float* Gpart  = ws + 612880;         // 8*8*65536 = 4194304 (16 MB)
    _Float16* Aph = (_Float16*)(ws + 4807184);   // 524288 halves
    _Float16* Apl = Aph + 524288;                // total ws ~21 MB

    k1_kernel<<<dim3(209), 256, 0, stream>>>(x, Wq, Wk, bq, bk, sxpart, W3, u2, w1, s1, S, Gpart);
    k2_kernel<<<dim3(272), 256, 0, stream>>>(Wv, Gpart, W3, u2, w1, s1, sxpart, T1, v2, s2, wvsx, S);
    ap_kernel<<<dim3(4, 8, 8), 256, 0, stream>>>(T1, W3, wvsx, u2, bv, v2, w1, s1, s2, Aph, Apl, cvec);
    gemmF_mfma<<<dim3(16, 2, 8), 256, 0, stream>>>(Aph, Apl, x, S, cvec, out);
}